// Round 7
// baseline (266.214 us; speedup 1.0000x reference)
//
#include <hip/hip_runtime.h>
#include <hip/hip_bf16.h>

#define DIM   384
#define HEADS 12
#define K2    9
#define HH    56
#define WW    56
#define HWP   3136
#define BB    8
#define AO    972      // attn-logit channels
#define AOP   976      // padded (lT row stride, 16B-aligned)
#define MCAT  1408     // 384 (v) + 1024 (attn) concatenated GEMM rows
#define PP    3200     // pixels padded to 25*128
#define PPAD  3600     // 60x60 zero-halo canvas for v
#define W60   60

#define WBLK     2688  // (MCAT*DIM + 384*DIM)/256
#define HALOBLK  696   // 8*464*48/256

typedef __hip_bfloat16 bf16;
typedef short bf16x8 __attribute__((ext_vector_type(8)));
typedef short bf16x4v __attribute__((ext_vector_type(4)));
typedef float f32x4 __attribute__((ext_vector_type(4)));
typedef float f32x2 __attribute__((ext_vector_type(2)));

static __device__ __forceinline__ float b2f(bf16 v) { return __bfloat162float(v); }
static __device__ __forceinline__ float bs2f(short s) {
    return __uint_as_float(((unsigned int)(unsigned short)s) << 16);
}
static __device__ __forceinline__ short f2bs(float f) {
    __hip_bfloat16 h = __float2bfloat16(f);
    return *(short*)&h;
}
// unpack one dword holding 2 bf16 (mem order: low half = even elem) -> 2 f32
static __device__ __forceinline__ f32x2 unpk(unsigned int u) {
    f32x2 r;
    r[0] = __uint_as_float(u << 16);
    r[1] = __uint_as_float(u & 0xffff0000u);
    return r;
}

// async global->LDS, 16B per lane. LDS dest must be wave-uniform base + lane*16.
static __device__ __forceinline__ void gl_lds16(const bf16* g, bf16* l) {
    __builtin_amdgcn_global_load_lds(
        (const __attribute__((address_space(1))) unsigned int*)g,
        (__attribute__((address_space(3))) unsigned int*)l, 16, 0, 0);
}

// ---------------------------------------------------------------------------
// Fused prep: weights->bf16 (wcat, wp), x -> xT transpose, vP halo zeroing.
// ---------------------------------------------------------------------------
__global__ __launch_bounds__(256) void prep_kernel(
        const float* __restrict__ x, const float* __restrict__ v_w,
        const float* __restrict__ attn_w, const float* __restrict__ proj_w,
        bf16* __restrict__ xT, bf16* __restrict__ wcat, bf16* __restrict__ wp,
        bf16* __restrict__ vP) {
    const int bid = blockIdx.x;
    if (bid < 400) {
        const int lane = threadIdx.x & 63, w = threadIdx.x >> 6;
        const int p = (bid % 50) * 64 + lane;
        const int b = bid / 50;
        bf16* dst = xT + ((size_t)b * PP + p) * DIM;
        if (p >= HWP) {
            bf16x8 z = {};
            for (int cg = w; cg < 48; cg += 4) *(bf16x8*)(dst + cg * 8) = z;
            return;
        }
        const float* src = x + (size_t)b * DIM * HWP + p;
        for (int cg = w; cg < 48; cg += 4) {
            bf16x8 v;
#pragma unroll
            for (int j = 0; j < 8; j++) v[j] = f2bs(src[(size_t)(cg * 8 + j) * HWP]);
            *(bf16x8*)(dst + cg * 8) = v;
        }
    } else if (bid < 400 + WBLK) {
        const int idx = (bid - 400) * 256 + threadIdx.x;
        const int NCAT = MCAT * DIM;
        if (idx < NCAT) {
            const int row = idx / DIM, col = idx % DIM;
            float v;
            if (row < 384) v = v_w[row * DIM + col];
            else { const int r2 = row - 384; v = (r2 < AO) ? attn_w[r2 * DIM + col] : 0.f; }
            *(short*)&wcat[idx] = f2bs(v);
        } else {
            const int j = idx - NCAT;
            if (j < 384 * DIM) *(short*)&wp[j] = f2bs(proj_w[j]);
        }
    } else {
        // halo zero: 464 halo pixels per batch, 48 x bf16x8 chunks each
        const int hidx = (bid - 400 - WBLK) * 256 + threadIdx.x;   // < 178176
        const int b = hidx / 22272;
        const int r = hidx % 22272;
        const int hp = r / 48, cgi = r % 48;
        int row, col;
        if (hp < 240) {                       // rows {0,1,58,59} full width
            const int rr = hp / 60;
            row = (rr < 2) ? rr : rr + 56;
            col = hp % 60;
        } else {                              // rows 2..57, cols {0,1,58,59}
            const int h2 = hp - 240;
            row = 2 + (h2 >> 2);
            const int c4 = h2 & 3;
            col = (c4 < 2) ? c4 : c4 + 56;
        }
        bf16x8 z = {};
        *(bf16x8*)(vP + ((size_t)b * PPAD + row * W60 + col) * DIM + cgi * 8) = z;
    }
}

// ---------------------------------------------------------------------------
// GEMM v6: 128x128 tile, BK=64, double-buffered LDS, COUNTED-vmcnt pipeline:
// raw s_barrier (no implicit vmcnt(0) drain) + s_waitcnt vmcnt(8) so the
// next tile's 8 loads/thread stay in flight ACROSS barriers (T4).
// 8-position XOR swizzle on the GLOBAL source address; LDS dest linear.
// ---------------------------------------------------------------------------
#define GEMM_STAGE(Ab, Bb, lA, lB, koff)                                       \
    {                                                                          \
        _Pragma("unroll")                                                      \
        for (int r = 0; r < 4; r++) {                                          \
            int idx = r * 256 + t;                                             \
            int row = idx >> 3;                                                \
            int kq = ((idx & 7) - (row >> 1)) & 7;                             \
            gl_lds16(Ab + (size_t)row * DIM + (koff) + kq * 8, lA + idx * 8);  \
        }                                                                      \
        _Pragma("unroll")                                                      \
        for (int r = 0; r < 4; r++) {                                          \
            int idx = r * 256 + t;                                             \
            int row = idx >> 3;                                                \
            int kq = ((idx & 7) - (row >> 1)) & 7;                             \
            gl_lds16(Bb + (size_t)row * DIM + (koff) + kq * 8, lB + idx * 8);  \
        }                                                                      \
    }

#define GEMM_COMPUTE(lA, lB, acc)                                              \
    __builtin_amdgcn_s_setprio(1);                                             \
    _Pragma("unroll")                                                          \
    for (int h = 0; h < 2; h++) {                                              \
        const int swzh = (((h << 2) + quad + (l16 >> 1)) & 7) * 8;             \
        bf16x8 af[4], bfr[4];                                                  \
        _Pragma("unroll")                                                      \
        for (int mt = 0; mt < 4; mt++)                                         \
            af[mt] = *(const bf16x8*)((lA) + (wm * 64 + mt * 16 + l16) * 64 + swzh); \
        _Pragma("unroll")                                                      \
        for (int nt = 0; nt < 4; nt++)                                         \
            bfr[nt] = *(const bf16x8*)((lB) + (wn * 64 + nt * 16 + l16) * 64 + swzh); \
        _Pragma("unroll")                                                      \
        for (int mt = 0; mt < 4; mt++)                                         \
            _Pragma("unroll")                                                  \
            for (int nt = 0; nt < 4; nt++)                                     \
                acc[mt][nt] = __builtin_amdgcn_mfma_f32_16x16x32_bf16(         \
                    af[mt], bfr[nt], acc[mt][nt], 0, 0, 0);                    \
    }                                                                          \
    __builtin_amdgcn_s_setprio(0);

// one pipelined K-step: stage next tile, wait for current (8 newest stay in
// flight), barrier, compute current, fence ds_reads, barrier.
#define GEMM_KSTEP(cA, cB, sA, sB, koff)                                       \
    GEMM_STAGE(Ab, Bb, sA, sB, koff)                                           \
    asm volatile("s_waitcnt vmcnt(8)" ::: "memory");                           \
    __builtin_amdgcn_s_barrier();                                              \
    GEMM_COMPUTE(cA, cB, acc)                                                  \
    asm volatile("s_waitcnt lgkmcnt(0)" ::: "memory");                         \
    __builtin_amdgcn_s_barrier();

// 6 K-tiles (DIM=384, BK=64), fully unrolled.
#define GEMM_MAIN_LOOP_V6(Ab, Bb, acc)                                         \
    GEMM_STAGE(Ab, Bb, lA0, lB0, 0)                                            \
    GEMM_KSTEP(lA0, lB0, lA1, lB1, 64)                                         \
    GEMM_KSTEP(lA1, lB1, lA0, lB0, 128)                                        \
    GEMM_KSTEP(lA0, lB0, lA1, lB1, 192)                                        \
    GEMM_KSTEP(lA1, lB1, lA0, lB0, 256)                                        \
    GEMM_KSTEP(lA0, lB0, lA1, lB1, 320)                                        \
    asm volatile("s_waitcnt vmcnt(0)" ::: "memory");                           \
    __builtin_amdgcn_s_barrier();                                              \
    GEMM_COMPUTE(lA1, lB1, acc)

// ---------------------------------------------------------------------------
// Merged GEMM1+2, XCD-swizzled 1-D grid (2200 blocks).
// swz = (bid&7)*275 + bid>>3 ; m fastest (11 m-tiles of one xT panel run
// consecutively on one XCD), each XCD owns exactly batch b = bid&7.
// Per-XCD L2 set: 2.46 MB xT slice + 1.08 MB wcat < 4 MB.
// ---------------------------------------------------------------------------
__global__ __launch_bounds__(256) void gemm12_kernel(
        const bf16* __restrict__ A, const bf16* __restrict__ Bt,
        const float* __restrict__ bias, bf16* __restrict__ vP,
        bf16* __restrict__ lT) {
    __shared__ bf16 lds[32768];         // 2 x (lA 8192 | lB 8192) = 64 KB
    bf16* lA0 = lds;
    bf16* lB0 = lds + 8192;
    bf16* lA1 = lds + 16384;
    bf16* lB1 = lds + 24576;
    const int t = threadIdx.x;
    const int lane = t & 63, w = t >> 6;
    const int wm = w & 1, wn = w >> 1;
    const int quad = lane >> 4, l16 = lane & 15;

    const int bid = blockIdx.x;
    const int swz = (bid & 7) * 275 + (bid >> 3);
    const int mtile = swz % 11;          // fastest: panel reuse within XCD
    const int nb = swz / 11;             // [25b, 25b+25)
    const int ntile = nb % 25;
    const int b = nb / 25;               // == bid & 7
    const int n0 = ntile * 128;
    const int m0 = mtile * 128;

    const bf16* Ab = A + (size_t)m0 * DIM;
    const bf16* Bb = Bt + ((size_t)b * PP + n0) * DIM;

    f32x4 acc[4][4] = {};
    GEMM_MAIN_LOOP_V6(Ab, Bb, acc)

    const bool isv = (m0 < 384);
    const int ch0 = isv ? m0 : m0 - 384;

    // wbuf lives in buf0 (lA0); last buf0 readers (T4 compute) are fenced by
    // their own lgkmcnt(0)+barrier; T5 compute reads buf1 only -> disjoint.
    bf16* wbuf = lds + w * 1152;   // wave-private, row stride 72 bf16
    const int nr = lane >> 2;
    const int mc = (lane & 3) * 16;
#pragma unroll
    for (int nt = 0; nt < 4; nt++) {
#pragma unroll
        for (int mt = 0; mt < 4; mt++) {
            float4 bi = make_float4(0.f, 0.f, 0.f, 0.f);
            if (isv) bi = *(const float4*)(bias + ch0 + wm * 64 + mt * 16 + quad * 4);
            bf16x4v pk;
            pk[0] = f2bs(acc[mt][nt][0] + bi.x);
            pk[1] = f2bs(acc[mt][nt][1] + bi.y);
            pk[2] = f2bs(acc[mt][nt][2] + bi.z);
            pk[3] = f2bs(acc[mt][nt][3] + bi.w);
            *(bf16x4v*)(wbuf + l16 * 72 + mt * 16 + quad * 4) = pk;
        }
        bf16x8 v0 = *(const bf16x8*)(wbuf + nr * 72 + mc);
        bf16x8 v1 = *(const bf16x8*)(wbuf + nr * 72 + mc + 8);
        const int p = n0 + wn * 64 + nt * 16 + nr;
        const int cc = ch0 + wm * 64 + mc;          // channel base of this 16-chunk
        if (p < HWP && (isv || cc < AOP)) {
            bf16* dp;
            if (isv) {
                const int y = p / WW;          // padded canvas: (y+2)*60 + x+2
                dp = vP + ((size_t)b * PPAD + p + y * 4 + 122) * DIM + cc;
            } else {
                dp = lT + ((size_t)b * PP + p) * AOP + cc;
            }
            *(bf16x8*)dp = v0;
            *(bf16x8*)(dp + 8) = v1;
        }
    }
}

// ---------------------------------------------------------------------------
// GEMM4: planar fp32 out [b][384][3136]. XCD-swizzled 1-D grid (600 blocks):
// swz = (bid&7)*75 + bid>>3 ; m fastest, each XCD owns batch b = bid&7.
// ---------------------------------------------------------------------------
__global__ __launch_bounds__(256) void gemm_planar_kernel(
        const bf16* __restrict__ A, const bf16* __restrict__ Bt,
        float* __restrict__ out) {
    __shared__ bf16 lds[32768];
    bf16* lA0 = lds;
    bf16* lB0 = lds + 8192;
    bf16* lA1 = lds + 16384;
    bf16* lB1 = lds + 24576;
    const int t = threadIdx.x;
    const int lane = t & 63, w = t >> 6;
    const int wm = w & 1, wn = w >> 1;
    const int quad = lane >> 4, l16 = lane & 15;

    const int bid = blockIdx.x;
    const int swz = (bid & 7) * 75 + (bid >> 3);
    const int mtile = swz % 3;
    const int nb = swz / 3;
    const int ntile = nb % 25;
    const int b = nb / 25;
    const int n0 = ntile * 128;
    const int m0 = mtile * 128;

    const bf16* Ab = A + (size_t)m0 * DIM;
    const bf16* Bb = Bt + ((size_t)b * PP + n0) * DIM;

    f32x4 acc[4][4] = {};
    GEMM_MAIN_LOOP_V6(Ab, Bb, acc)

#pragma unroll
    for (int mt = 0; mt < 4; mt++) {
#pragma unroll
        for (int nt = 0; nt < 4; nt++) {
            int p = n0 + wn * 64 + nt * 16 + l16;
            if (p >= HWP) continue;
#pragma unroll
            for (int reg = 0; reg < 4; reg++) {
                int o = m0 + wm * 64 + mt * 16 + quad * 4 + reg;
                out[((size_t)b * DIM + o) * HWP + p] = acc[mt][nt][reg];
            }
        }
    }
}

// ---------------------------------------------------------------------------
// attn+fold: 8 pixels per block, 384 threads. 1-D grid 3136 blocks:
// b = bid&7 (each XCD owns one batch: vP slice 2.76 MB L2-resident).
// v6: stage C software-pipelines V-row loads (2x5 uint4 double buffer) so
// ~10 loads stay in flight; launch_bounds(384,4) lifts the 32-VGPR cap
// that was serializing them (round-5 counters: VGPR=32, VALUBusy 60%).
// ---------------------------------------------------------------------------
__global__ __launch_bounds__(384, 4) void attn_fold_kernel(
        const bf16* __restrict__ lT, const bf16* __restrict__ vP,
        bf16* __restrict__ cT) {
    __shared__ bf16 P[8 * 9 * 12 * 9];     // [px][i][n][d]  19440 B
    __shared__ float Wf[8 * 25 * 12];      // [px][off][n]    9600 B
    const int t = threadIdx.x;
    const int b = blockIdx.x & 7;
    const int pix0 = (blockIdx.x >> 3) * 8;
    const int Y = pix0 / WW, X0 = pix0 % WW;

    // ---- stage A: softmaxes at window centers (direct global reads)
    for (int r = t; r < 864; r += 384) {
        const int px = r / 108, rem = r % 108;
        const int i = rem / 12, n = rem % 12;
        const int ir = i / 3, ic = i % 3;
        const int yi = Y + 1 - ir, xi = X0 + px + 1 - ic;
        bf16* Pd = &P[r * 9];   // r*9 == ((px*9+i)*12+n)*9
        if (yi < 0 || yi >= HH || xi < 0 || xi >= WW) {
#pragma unroll
            for (int d = 0; d < K2; d++) *(short*)&Pd[d] = 0;
        } else {
            const bf16* base = lT + ((size_t)b * PP + yi * WW + xi) * AOP + i * 108 + n;
            float lv[K2];
            float m = -1e30f;
#pragma unroll
            for (int d = 0; d < K2; d++) {
                lv[d] = b2f(base[d * 12]);
                m = fmaxf(m, lv[d]);
            }
            float s = 0.f;
#pragma unroll
            for (int d = 0; d < K2; d++) { lv[d] = __expf(lv[d] - m); s += lv[d]; }
            const float inv = 1.f / s;
#pragma unroll
            for (int d = 0; d < K2; d++) *(short*)&Pd[d] = f2bs(lv[d] * inv);
        }
    }
    __syncthreads();

    // ---- stage B: effective 5x5 weights; thread owns (off,n), loops px
    if (t < 300) {
        const int off = t / 12, n = t % 12;
        const int dy = off / 5 - 2, dx = off % 5 - 2;
        const int ir_lo = max(0, -dy), ir_hi = min(2, 2 - dy);
        const int ic_lo = max(0, -dx), ic_hi = min(2, 2 - dx);
#pragma unroll
        for (int px = 0; px < 8; px++) {
            float wsum = 0.f;
            for (int ir = ir_lo; ir <= ir_hi; ir++)
                for (int ic = ic_lo; ic <= ic_hi; ic++) {
                    const int i = ir * 3 + ic;
                    const int d = (dy + ir) * 3 + (dx + ic);
                    wsum += b2f(P[((px * 9 + i) * 12 + n) * 9 + d]);
                }
            Wf[(px * 25 + off) * 12 + n] = wsum;
        }
    }
    __syncthreads();

    // ---- stage C: 5x5 gather on zero-padded canvas, packed fma,
    // 2-row software pipeline (all indices compile-time -> registers).
    const int px = t / 48, cg = t % 48;
    const int X = X0 + px;
    const int n = cg >> 2;
    const float* Wp = &Wf[px * 300 + n];
    const bf16* vbp = vP + ((size_t)b * PPAD + (size_t)(Y + 2) * W60 + (X + 2)) * DIM + cg * 8;
    uint4 va[5], vb2[5];
#pragma unroll
    for (int dx = 0; dx < 5; dx++)
        va[dx] = *(const uint4*)(vbp + (-2) * (W60 * DIM) + (dx - 2) * DIM);
    f32x2 a2[4] = {};
#pragma unroll
    for (int dy = -2; dy <= 2; dy++) {
        if (dy < 2) {      // preload next row into the buffer not in use
            const bf16* nrow = vbp + (dy + 1) * (W60 * DIM);
            if (((dy + 2) & 1) == 0) {
#pragma unroll
                for (int dx = 0; dx < 5; dx++) vb2[dx] = *(const uint4*)(nrow + (dx - 2) * DIM);
            } else {
#pragma unroll
                for (int dx = 0; dx < 5; dx++) va[dx] = *(const uint4*)(nrow + (dx - 2) * DIM);
            }
        }
        const float* wrow = Wp + (dy + 2) * 60;   // 5*12
#pragma unroll
        for (int dx = 0; dx < 5; dx++) {
            const float w = wrow[dx * 12];
            const uint4 d = (((dy + 2) & 1) == 0) ? va[dx] : vb2[dx];
            f32x2 w2; w2[0] = w; w2[1] = w;
            a2[0] = __builtin_elementwise_fma(unpk(d.x), w2, a2[0]);
            a2[1] = __builtin_elementwise_fma(unpk(d.y), w2, a2[1]);
            a2[2] = __builtin_elementwise_fma(unpk(d.z), w2, a2[2]);
            a2[3] = __builtin_elementwise_fma(unpk(d.w), w2, a2[3]);
        }
    }
    bf16x8 po;
#pragma unroll
    for (int j = 0; j < 4; j++) {
        po[2 * j]     = f2bs(a2[j][0]);
        po[2 * j + 1] = f2bs(a2[j][1]);
    }
    *(bf16x8*)(cT + ((size_t)b * PP + pix0 + px) * DIM + cg * 8) = po;
}

// ---------------------------------------------------------------------------
extern "C" void kernel_launch(void* const* d_in, const int* in_sizes, int n_in,
                              void* d_out, int out_size, void* d_ws, size_t ws_size,
                              hipStream_t stream) {
    const float* x      = (const float*)d_in[0];
    const float* v_w    = (const float*)d_in[1];
    const float* v_b    = (const float*)d_in[2];
    const float* attn_w = (const float*)d_in[3];
    const float* proj_w = (const float*)d_in[4];
    float* out = (float*)d_out;

    bf16* xT    = (bf16*)d_ws;                        // [8][3200][384]
    bf16* vP    = xT + (size_t)BB * PP * DIM;         // [8][3600][384] padded canvas
    bf16* lT    = vP + (size_t)BB * PPAD * DIM;       // [8][3200][976]
    bf16* wcat  = lT + (size_t)BB * PP * AOP;         // [1408][384]
    bf16* wp    = wcat + (size_t)MCAT * DIM;          // [384][384]
    bf16* cT    = xT;   // canvasT aliases xT (xT dead after gemm12)

    const int nprep = 400 + WBLK + HALOBLK;
    prep_kernel<<<nprep, 256, 0, stream>>>(x, v_w, attn_w, proj_w, xT, wcat, wp, vP);

    // 1+2) value projection (-> padded canvas) + attention logits (merged)
    gemm12_kernel<<<2200, 256, 0, stream>>>(wcat, xT, v_b, vP, lT);
    // 3) fused softmax + weight-reduce + 5x5 gather -> cT
    attn_fold_kernel<<<3136, 384, 0, stream>>>(lT, vP, cT);
    // 4) output projection -> out (planar fp32)
    gemm_planar_kernel<<<600, 256, 0, stream>>>(wp, cT, out);
}

// Round 8
// 230.054 us; speedup vs baseline: 1.1572x; 1.1572x over previous
//
#include <hip/hip_runtime.h>
#include <hip/hip_bf16.h>

#define DIM   384
#define HEADS 12
#define K2    9
#define HH    56
#define WW    56
#define HWP   3136
#define BB    8
#define AO    972      // attn-logit channels
#define AOP   976      // padded (lT row stride, 16B-aligned)
#define MCAT  1408     // 384 (v) + 1024 (attn) concatenated GEMM rows
#define PP    3200     // pixels padded to 25*128
#define PPAD  3600     // 60x60 zero-halo canvas for v
#define W60   60

#define WBLK     2688  // (MCAT*DIM + 384*DIM)/256
#define HALOBLK  696   // 8*464*48/256

typedef __hip_bfloat16 bf16;
typedef short bf16x8 __attribute__((ext_vector_type(8)));
typedef short bf16x4v __attribute__((ext_vector_type(4)));
typedef float f32x4 __attribute__((ext_vector_type(4)));
typedef float f32x2 __attribute__((ext_vector_type(2)));

static __device__ __forceinline__ float b2f(bf16 v) { return __bfloat162float(v); }
static __device__ __forceinline__ float bs2f(short s) {
    return __uint_as_float(((unsigned int)(unsigned short)s) << 16);
}
static __device__ __forceinline__ short f2bs(float f) {
    __hip_bfloat16 h = __float2bfloat16(f);
    return *(short*)&h;
}
// unpack one dword holding 2 bf16 (mem order: low half = even elem) -> 2 f32
static __device__ __forceinline__ f32x2 unpk(unsigned int u) {
    f32x2 r;
    r[0] = __uint_as_float(u << 16);
    r[1] = __uint_as_float(u & 0xffff0000u);
    return r;
}

// async global->LDS, 16B per lane. LDS dest must be wave-uniform base + lane*16.
static __device__ __forceinline__ void gl_lds16(const bf16* g, bf16* l) {
    __builtin_amdgcn_global_load_lds(
        (const __attribute__((address_space(1))) unsigned int*)g,
        (__attribute__((address_space(3))) unsigned int*)l, 16, 0, 0);
}

// ---------------------------------------------------------------------------
// Fused prep: weights->bf16 (wcat, wp), x -> xT transpose, vP halo zeroing.
// ---------------------------------------------------------------------------
__global__ __launch_bounds__(256) void prep_kernel(
        const float* __restrict__ x, const float* __restrict__ v_w,
        const float* __restrict__ attn_w, const float* __restrict__ proj_w,
        bf16* __restrict__ xT, bf16* __restrict__ wcat, bf16* __restrict__ wp,
        bf16* __restrict__ vP) {
    const int bid = blockIdx.x;
    if (bid < 400) {
        const int lane = threadIdx.x & 63, w = threadIdx.x >> 6;
        const int p = (bid % 50) * 64 + lane;
        const int b = bid / 50;
        bf16* dst = xT + ((size_t)b * PP + p) * DIM;
        if (p >= HWP) {
            bf16x8 z = {};
            for (int cg = w; cg < 48; cg += 4) *(bf16x8*)(dst + cg * 8) = z;
            return;
        }
        const float* src = x + (size_t)b * DIM * HWP + p;
        for (int cg = w; cg < 48; cg += 4) {
            bf16x8 v;
#pragma unroll
            for (int j = 0; j < 8; j++) v[j] = f2bs(src[(size_t)(cg * 8 + j) * HWP]);
            *(bf16x8*)(dst + cg * 8) = v;
        }
    } else if (bid < 400 + WBLK) {
        const int idx = (bid - 400) * 256 + threadIdx.x;
        const int NCAT = MCAT * DIM;
        if (idx < NCAT) {
            const int row = idx / DIM, col = idx % DIM;
            float v;
            if (row < 384) v = v_w[row * DIM + col];
            else { const int r2 = row - 384; v = (r2 < AO) ? attn_w[r2 * DIM + col] : 0.f; }
            *(short*)&wcat[idx] = f2bs(v);
        } else {
            const int j = idx - NCAT;
            if (j < 384 * DIM) *(short*)&wp[j] = f2bs(proj_w[j]);
        }
    } else {
        // halo zero: 464 halo pixels per batch, 48 x bf16x8 chunks each
        const int hidx = (bid - 400 - WBLK) * 256 + threadIdx.x;   // < 178176
        const int b = hidx / 22272;
        const int r = hidx % 22272;
        const int hp = r / 48, cgi = r % 48;
        int row, col;
        if (hp < 240) {                       // rows {0,1,58,59} full width
            const int rr = hp / 60;
            row = (rr < 2) ? rr : rr + 56;
            col = hp % 60;
        } else {                              // rows 2..57, cols {0,1,58,59}
            const int h2 = hp - 240;
            row = 2 + (h2 >> 2);
            const int c4 = h2 & 3;
            col = (c4 < 2) ? c4 : c4 + 56;
        }
        bf16x8 z = {};
        *(bf16x8*)(vP + ((size_t)b * PPAD + row * W60 + col) * DIM + cgi * 8) = z;
    }
}

// ---------------------------------------------------------------------------
// GEMM v6: 128x128 tile, BK=64, double-buffered LDS, COUNTED-vmcnt pipeline:
// raw s_barrier (no implicit vmcnt(0) drain) + s_waitcnt vmcnt(8) so the
// next tile's 8 loads/thread stay in flight ACROSS barriers (T4).
// 8-position XOR swizzle on the GLOBAL source address; LDS dest linear.
// ---------------------------------------------------------------------------
#define GEMM_STAGE(Ab, Bb, lA, lB, koff)                                       \
    {                                                                          \
        _Pragma("unroll")                                                      \
        for (int r = 0; r < 4; r++) {                                          \
            int idx = r * 256 + t;                                             \
            int row = idx >> 3;                                                \
            int kq = ((idx & 7) - (row >> 1)) & 7;                             \
            gl_lds16(Ab + (size_t)row * DIM + (koff) + kq * 8, lA + idx * 8);  \
        }                                                                      \
        _Pragma("unroll")                                                      \
        for (int r = 0; r < 4; r++) {                                          \
            int idx = r * 256 + t;                                             \
            int row = idx >> 3;                                                \
            int kq = ((idx & 7) - (row >> 1)) & 7;                             \
            gl_lds16(Bb + (size_t)row * DIM + (koff) + kq * 8, lB + idx * 8);  \
        }                                                                      \
    }

#define GEMM_COMPUTE(lA, lB, acc)                                              \
    __builtin_amdgcn_s_setprio(1);                                             \
    _Pragma("unroll")                                                          \
    for (int h = 0; h < 2; h++) {                                              \
        const int swzh = (((h << 2) + quad + (l16 >> 1)) & 7) * 8;             \
        bf16x8 af[4], bfr[4];                                                  \
        _Pragma("unroll")                                                      \
        for (int mt = 0; mt < 4; mt++)                                         \
            af[mt] = *(const bf16x8*)((lA) + (wm * 64 + mt * 16 + l16) * 64 + swzh); \
        _Pragma("unroll")                                                      \
        for (int nt = 0; nt < 4; nt++)                                         \
            bfr[nt] = *(const bf16x8*)((lB) + (wn * 64 + nt * 16 + l16) * 64 + swzh); \
        _Pragma("unroll")                                                      \
        for (int mt = 0; mt < 4; mt++)                                         \
            _Pragma("unroll")                                                  \
            for (int nt = 0; nt < 4; nt++)                                     \
                acc[mt][nt] = __builtin_amdgcn_mfma_f32_16x16x32_bf16(         \
                    af[mt], bfr[nt], acc[mt][nt], 0, 0, 0);                    \
    }                                                                          \
    __builtin_amdgcn_s_setprio(0);

// one pipelined K-step: stage next tile, wait for current (8 newest stay in
// flight), barrier, compute current, fence ds_reads, barrier.
#define GEMM_KSTEP(cA, cB, sA, sB, koff)                                       \
    GEMM_STAGE(Ab, Bb, sA, sB, koff)                                           \
    asm volatile("s_waitcnt vmcnt(8)" ::: "memory");                           \
    __builtin_amdgcn_s_barrier();                                              \
    GEMM_COMPUTE(cA, cB, acc)                                                  \
    asm volatile("s_waitcnt lgkmcnt(0)" ::: "memory");                         \
    __builtin_amdgcn_s_barrier();

// 6 K-tiles (DIM=384, BK=64), fully unrolled.
#define GEMM_MAIN_LOOP_V6(Ab, Bb, acc)                                         \
    GEMM_STAGE(Ab, Bb, lA0, lB0, 0)                                            \
    GEMM_KSTEP(lA0, lB0, lA1, lB1, 64)                                         \
    GEMM_KSTEP(lA1, lB1, lA0, lB0, 128)                                        \
    GEMM_KSTEP(lA0, lB0, lA1, lB1, 192)                                        \
    GEMM_KSTEP(lA1, lB1, lA0, lB0, 256)                                        \
    GEMM_KSTEP(lA0, lB0, lA1, lB1, 320)                                        \
    asm volatile("s_waitcnt vmcnt(0)" ::: "memory");                           \
    __builtin_amdgcn_s_barrier();                                              \
    GEMM_COMPUTE(lA1, lB1, acc)

// ---------------------------------------------------------------------------
// Merged GEMM1+2, XCD-swizzled 1-D grid (2200 blocks).
// swz = (bid&7)*275 + bid>>3 ; m fastest (11 m-tiles of one xT panel run
// consecutively on one XCD), each XCD owns exactly batch b = bid&7.
// Per-XCD L2 set: 2.46 MB xT slice + 1.08 MB wcat < 4 MB.
// ---------------------------------------------------------------------------
__global__ __launch_bounds__(256) void gemm12_kernel(
        const bf16* __restrict__ A, const bf16* __restrict__ Bt,
        const float* __restrict__ bias, bf16* __restrict__ vP,
        bf16* __restrict__ lT) {
    __shared__ bf16 lds[32768];         // 2 x (lA 8192 | lB 8192) = 64 KB
    bf16* lA0 = lds;
    bf16* lB0 = lds + 8192;
    bf16* lA1 = lds + 16384;
    bf16* lB1 = lds + 24576;
    const int t = threadIdx.x;
    const int lane = t & 63, w = t >> 6;
    const int wm = w & 1, wn = w >> 1;
    const int quad = lane >> 4, l16 = lane & 15;

    const int bid = blockIdx.x;
    const int swz = (bid & 7) * 275 + (bid >> 3);
    const int mtile = swz % 11;          // fastest: panel reuse within XCD
    const int nb = swz / 11;             // [25b, 25b+25)
    const int ntile = nb % 25;
    const int b = nb / 25;               // == bid & 7
    const int n0 = ntile * 128;
    const int m0 = mtile * 128;

    const bf16* Ab = A + (size_t)m0 * DIM;
    const bf16* Bb = Bt + ((size_t)b * PP + n0) * DIM;

    f32x4 acc[4][4] = {};
    GEMM_MAIN_LOOP_V6(Ab, Bb, acc)

    const bool isv = (m0 < 384);
    const int ch0 = isv ? m0 : m0 - 384;

    // wbuf lives in buf0 (lA0); last buf0 readers (T4 compute) are fenced by
    // their own lgkmcnt(0)+barrier; T5 compute reads buf1 only -> disjoint.
    bf16* wbuf = lds + w * 1152;   // wave-private, row stride 72 bf16
    const int nr = lane >> 2;
    const int mc = (lane & 3) * 16;
#pragma unroll
    for (int nt = 0; nt < 4; nt++) {
#pragma unroll
        for (int mt = 0; mt < 4; mt++) {
            float4 bi = make_float4(0.f, 0.f, 0.f, 0.f);
            if (isv) bi = *(const float4*)(bias + ch0 + wm * 64 + mt * 16 + quad * 4);
            bf16x4v pk;
            pk[0] = f2bs(acc[mt][nt][0] + bi.x);
            pk[1] = f2bs(acc[mt][nt][1] + bi.y);
            pk[2] = f2bs(acc[mt][nt][2] + bi.z);
            pk[3] = f2bs(acc[mt][nt][3] + bi.w);
            *(bf16x4v*)(wbuf + l16 * 72 + mt * 16 + quad * 4) = pk;
        }
        bf16x8 v0 = *(const bf16x8*)(wbuf + nr * 72 + mc);
        bf16x8 v1 = *(const bf16x8*)(wbuf + nr * 72 + mc + 8);
        const int p = n0 + wn * 64 + nt * 16 + nr;
        const int cc = ch0 + wm * 64 + mc;          // channel base of this 16-chunk
        if (p < HWP && (isv || cc < AOP)) {
            bf16* dp;
            if (isv) {
                const int y = p / WW;          // padded canvas: (y+2)*60 + x+2
                dp = vP + ((size_t)b * PPAD + p + y * 4 + 122) * DIM + cc;
            } else {
                dp = lT + ((size_t)b * PP + p) * AOP + cc;
            }
            *(bf16x8*)dp = v0;
            *(bf16x8*)(dp + 8) = v1;
        }
    }
}

// ---------------------------------------------------------------------------
// GEMM4: planar fp32 out [b][384][3136]. XCD-swizzled 1-D grid (600 blocks):
// swz = (bid&7)*75 + bid>>3 ; m fastest, each XCD owns batch b = bid&7.
// ---------------------------------------------------------------------------
__global__ __launch_bounds__(256) void gemm_planar_kernel(
        const bf16* __restrict__ A, const bf16* __restrict__ Bt,
        float* __restrict__ out) {
    __shared__ bf16 lds[32768];
    bf16* lA0 = lds;
    bf16* lB0 = lds + 8192;
    bf16* lA1 = lds + 16384;
    bf16* lB1 = lds + 24576;
    const int t = threadIdx.x;
    const int lane = t & 63, w = t >> 6;
    const int wm = w & 1, wn = w >> 1;
    const int quad = lane >> 4, l16 = lane & 15;

    const int bid = blockIdx.x;
    const int swz = (bid & 7) * 75 + (bid >> 3);
    const int mtile = swz % 3;
    const int nb = swz / 3;
    const int ntile = nb % 25;
    const int b = nb / 25;
    const int n0 = ntile * 128;
    const int m0 = mtile * 128;

    const bf16* Ab = A + (size_t)m0 * DIM;
    const bf16* Bb = Bt + ((size_t)b * PP + n0) * DIM;

    f32x4 acc[4][4] = {};
    GEMM_MAIN_LOOP_V6(Ab, Bb, acc)

#pragma unroll
    for (int mt = 0; mt < 4; mt++) {
#pragma unroll
        for (int nt = 0; nt < 4; nt++) {
            int p = n0 + wn * 64 + nt * 16 + l16;
            if (p >= HWP) continue;
#pragma unroll
            for (int reg = 0; reg < 4; reg++) {
                int o = m0 + wm * 64 + mt * 16 + quad * 4 + reg;
                out[((size_t)b * DIM + o) * HWP + p] = acc[mt][nt][reg];
            }
        }
    }
}

// ---------------------------------------------------------------------------
// attn+fold: 8 pixels per block, 384 threads. 1-D grid 3136 blocks:
// b = bid&7 (each XCD owns one batch: vP slice 2.76 MB L2-resident).
// v8 stage C: flat uint4 vv[25], ALL indices compile-time (rule #20 safe),
// all 25 loads issued before any fma (sched_barrier(0) fence) -> one L2
// latency stall instead of ~10 serialized ones. Plain launch_bounds(384).
// ---------------------------------------------------------------------------
__global__ __launch_bounds__(384) void attn_fold_kernel(
        const bf16* __restrict__ lT, const bf16* __restrict__ vP,
        bf16* __restrict__ cT) {
    __shared__ bf16 P[8 * 9 * 12 * 9];     // [px][i][n][d]  19440 B
    __shared__ float Wf[8 * 25 * 12];      // [px][off][n]    9600 B
    const int t = threadIdx.x;
    const int b = blockIdx.x & 7;
    const int pix0 = (blockIdx.x >> 3) * 8;
    const int Y = pix0 / WW, X0 = pix0 % WW;

    // ---- stage A: softmaxes at window centers (direct global reads)
    for (int r = t; r < 864; r += 384) {
        const int px = r / 108, rem = r % 108;
        const int i = rem / 12, n = rem % 12;
        const int ir = i / 3, ic = i % 3;
        const int yi = Y + 1 - ir, xi = X0 + px + 1 - ic;
        bf16* Pd = &P[r * 9];   // r*9 == ((px*9+i)*12+n)*9
        if (yi < 0 || yi >= HH || xi < 0 || xi >= WW) {
#pragma unroll
            for (int d = 0; d < K2; d++) *(short*)&Pd[d] = 0;
        } else {
            const bf16* base = lT + ((size_t)b * PP + yi * WW + xi) * AOP + i * 108 + n;
            float lv[K2];
            float m = -1e30f;
#pragma unroll
            for (int d = 0; d < K2; d++) {
                lv[d] = b2f(base[d * 12]);
                m = fmaxf(m, lv[d]);
            }
            float s = 0.f;
#pragma unroll
            for (int d = 0; d < K2; d++) { lv[d] = __expf(lv[d] - m); s += lv[d]; }
            const float inv = 1.f / s;
#pragma unroll
            for (int d = 0; d < K2; d++) *(short*)&Pd[d] = f2bs(lv[d] * inv);
        }
    }
    __syncthreads();

    // ---- stage B: effective 5x5 weights; thread owns (off,n), loops px
    if (t < 300) {
        const int off = t / 12, n = t % 12;
        const int dy = off / 5 - 2, dx = off % 5 - 2;
        const int ir_lo = max(0, -dy), ir_hi = min(2, 2 - dy);
        const int ic_lo = max(0, -dx), ic_hi = min(2, 2 - dx);
#pragma unroll
        for (int px = 0; px < 8; px++) {
            float wsum = 0.f;
            for (int ir = ir_lo; ir <= ir_hi; ir++)
                for (int ic = ic_lo; ic <= ic_hi; ic++) {
                    const int i = ir * 3 + ic;
                    const int d = (dy + ir) * 3 + (dx + ic);
                    wsum += b2f(P[((px * 9 + i) * 12 + n) * 9 + d]);
                }
            Wf[(px * 25 + off) * 12 + n] = wsum;
        }
    }
    __syncthreads();

    // ---- stage C: 5x5 gather on zero-padded canvas, packed fma.
    // All 25 taps loaded into registers first (static indices only),
    // then fma sweep. sched_barrier(0) keeps the loads clustered.
    const int px = t / 48, cg = t % 48;
    const int X = X0 + px;
    const int n = cg >> 2;
    const float* Wp = &Wf[px * 300 + n];
    const bf16* vbp = vP + ((size_t)b * PPAD + (size_t)(Y + 2) * W60 + (X + 2)) * DIM + cg * 8;
    uint4 vv[25];
#pragma unroll
    for (int k = 0; k < 25; k++) {
        const int dy = k / 5 - 2, dx = k % 5 - 2;
        vv[k] = *(const uint4*)(vbp + dy * (W60 * DIM) + dx * DIM);
    }
    __builtin_amdgcn_sched_barrier(0);
    f32x2 a2[4] = {};
#pragma unroll
    for (int k = 0; k < 25; k++) {
        const float w = Wp[k * 12];
        f32x2 w2; w2[0] = w; w2[1] = w;
        a2[0] = __builtin_elementwise_fma(unpk(vv[k].x), w2, a2[0]);
        a2[1] = __builtin_elementwise_fma(unpk(vv[k].y), w2, a2[1]);
        a2[2] = __builtin_elementwise_fma(unpk(vv[k].z), w2, a2[2]);
        a2[3] = __builtin_elementwise_fma(unpk(vv[k].w), w2, a2[3]);
    }
    bf16x8 po;
#pragma unroll
    for (int j = 0; j < 4; j++) {
        po[2 * j]     = f2bs(a2[j][0]);
        po[2 * j + 1] = f2bs(a2[j][1]);
    }
    *(bf16x8*)(cT + ((size_t)b * PP + pix0 + px) * DIM + cg * 8) = po;
}

// ---------------------------------------------------------------------------
extern "C" void kernel_launch(void* const* d_in, const int* in_sizes, int n_in,
                              void* d_out, int out_size, void* d_ws, size_t ws_size,
                              hipStream_t stream) {
    const float* x      = (const float*)d_in[0];
    const float* v_w    = (const float*)d_in[1];
    const float* v_b    = (const float*)d_in[2];
    const float* attn_w = (const float*)d_in[3];
    const float* proj_w = (const float*)d_in[4];
    float* out = (float*)d_out;

    bf16* xT    = (bf16*)d_ws;                        // [8][3200][384]
    bf16* vP    = xT + (size_t)BB * PP * DIM;         // [8][3600][384] padded canvas
    bf16* lT    = vP + (size_t)BB * PPAD * DIM;       // [8][3200][976]
    bf16* wcat  = lT + (size_t)BB * PP * AOP;         // [1408][384]
    bf16* wp    = wcat + (size_t)MCAT * DIM;          // [384][384]
    bf16* cT    = xT;   // canvasT aliases xT (xT dead after gemm12)

    const int nprep = 400 + WBLK + HALOBLK;
    prep_kernel<<<nprep, 256, 0, stream>>>(x, v_w, attn_w, proj_w, xT, wcat, wp, vP);

    // 1+2) value projection (-> padded canvas) + attention logits (merged)
    gemm12_kernel<<<2200, 256, 0, stream>>>(wcat, xT, v_b, vP, lT);
    // 3) fused softmax + weight-reduce + 5x5 gather -> cT
    attn_fold_kernel<<<3136, 384, 0, stream>>>(lT, vP, cT);
    // 4) output projection -> out (planar fp32)
    gemm_planar_kernel<<<600, 256, 0, stream>>>(wp, cT, out);
}

// Round 11
// 201.656 us; speedup vs baseline: 1.3201x; 1.1408x over previous
//
#include <hip/hip_runtime.h>
#include <hip/hip_bf16.h>

#define DIM   384
#define HEADS 12
#define K2    9
#define HH    56
#define WW    56
#define HWP   3136
#define BB    8
#define AO    972      // attn-logit channels
#define AOP   976      // padded (lT row stride, 16B-aligned)
#define MCAT  1408     // 384 (v) + 1024 (attn) concatenated GEMM rows
#define PP    3200     // pixels padded to 25*128
#define PPAD  3600     // 60x60 zero-halo canvas for v
#define W60   60

#define WBLK     2688  // (MCAT*DIM + 384*DIM)/256
#define HALOBLK  696   // 8*464*48/256

typedef __hip_bfloat16 bf16;
typedef short bf16x8 __attribute__((ext_vector_type(8)));
typedef short bf16x4v __attribute__((ext_vector_type(4)));
typedef float f32x4 __attribute__((ext_vector_type(4)));
typedef float f32x2 __attribute__((ext_vector_type(2)));

static __device__ __forceinline__ float b2f(bf16 v) { return __bfloat162float(v); }
static __device__ __forceinline__ float bs2f(short s) {
    return __uint_as_float(((unsigned int)(unsigned short)s) << 16);
}
static __device__ __forceinline__ short f2bs(float f) {
    __hip_bfloat16 h = __float2bfloat16(f);
    return *(short*)&h;
}
// unpack one dword holding 2 bf16 (mem order: low half = even elem) -> 2 f32
static __device__ __forceinline__ f32x2 unpk(unsigned int u) {
    f32x2 r;
    r[0] = __uint_as_float(u << 16);
    r[1] = __uint_as_float(u & 0xffff0000u);
    return r;
}

// async global->LDS, 16B per lane. LDS dest must be wave-uniform base + lane*16.
static __device__ __forceinline__ void gl_lds16(const bf16* g, bf16* l) {
    __builtin_amdgcn_global_load_lds(
        (const __attribute__((address_space(1))) unsigned int*)g,
        (__attribute__((address_space(3))) unsigned int*)l, 16, 0, 0);
}

// ---------------------------------------------------------------------------
// Fused prep: weights->bf16 (wcat, wp), x -> xT transpose, vP halo zeroing.
// attn rows PERMUTED: wcat row 384+c' holds attn_w row (i*9+d)*12+n where
// c' = n*81 + i*9 + d  -> stage A's 9 d-loads become 18 contiguous bytes.
// ---------------------------------------------------------------------------
__global__ __launch_bounds__(256) void prep_kernel(
        const float* __restrict__ x, const float* __restrict__ v_w,
        const float* __restrict__ attn_w, const float* __restrict__ proj_w,
        bf16* __restrict__ xT, bf16* __restrict__ wcat, bf16* __restrict__ wp,
        bf16* __restrict__ vP) {
    const int bid = blockIdx.x;
    if (bid < 400) {
        const int lane = threadIdx.x & 63, w = threadIdx.x >> 6;
        const int p = (bid % 50) * 64 + lane;
        const int b = bid / 50;
        bf16* dst = xT + ((size_t)b * PP + p) * DIM;
        if (p >= HWP) {
            bf16x8 z = {};
            for (int cg = w; cg < 48; cg += 4) *(bf16x8*)(dst + cg * 8) = z;
            return;
        }
        const float* src = x + (size_t)b * DIM * HWP + p;
        for (int cg = w; cg < 48; cg += 4) {
            bf16x8 v;
#pragma unroll
            for (int j = 0; j < 8; j++) v[j] = f2bs(src[(size_t)(cg * 8 + j) * HWP]);
            *(bf16x8*)(dst + cg * 8) = v;
        }
    } else if (bid < 400 + WBLK) {
        const int idx = (bid - 400) * 256 + threadIdx.x;
        const int NCAT = MCAT * DIM;
        if (idx < NCAT) {
            const int row = idx / DIM, col = idx % DIM;
            float v;
            if (row < 384) v = v_w[row * DIM + col];
            else {
                const int r2 = row - 384;      // destination channel c'
                if (r2 < AO) {
                    const int n = r2 / 81, rem = r2 % 81;
                    const int i = rem / 9, d = rem % 9;
                    v = attn_w[((i * 9 + d) * 12 + n) * DIM + col];
                } else v = 0.f;
            }
            *(short*)&wcat[idx] = f2bs(v);
        } else {
            const int j = idx - NCAT;
            if (j < 384 * DIM) *(short*)&wp[j] = f2bs(proj_w[j]);
        }
    } else {
        // halo zero: 464 halo pixels per batch, 48 x bf16x8 chunks each
        const int hidx = (bid - 400 - WBLK) * 256 + threadIdx.x;   // < 178176
        const int b = hidx / 22272;
        const int r = hidx % 22272;
        const int hp = r / 48, cgi = r % 48;
        int row, col;
        if (hp < 240) {                       // rows {0,1,58,59} full width
            const int rr = hp / 60;
            row = (rr < 2) ? rr : rr + 56;
            col = hp % 60;
        } else {                              // rows 2..57, cols {0,1,58,59}
            const int h2 = hp - 240;
            row = 2 + (h2 >> 2);
            const int c4 = h2 & 3;
            col = (c4 < 2) ? c4 : c4 + 56;
        }
        bf16x8 z = {};
        *(bf16x8*)(vP + ((size_t)b * PPAD + row * W60 + col) * DIM + cgi * 8) = z;
    }
}

// ---------------------------------------------------------------------------
// GEMM v6: 128x128 tile, BK=64, double-buffered LDS, COUNTED-vmcnt pipeline:
// raw s_barrier (no implicit vmcnt(0) drain) + s_waitcnt vmcnt(8) so the
// next tile's 8 loads/thread stay in flight ACROSS barriers (T4).
// 8-position XOR swizzle on the GLOBAL source address; LDS dest linear.
// ---------------------------------------------------------------------------
#define GEMM_STAGE(Ab, Bb, lA, lB, koff)                                       \
    {                                                                          \
        _Pragma("unroll")                                                      \
        for (int r = 0; r < 4; r++) {                                          \
            int idx = r * 256 + t;                                             \
            int row = idx >> 3;                                                \
            int kq = ((idx & 7) - (row >> 1)) & 7;                             \
            gl_lds16(Ab + (size_t)row * DIM + (koff) + kq * 8, lA + idx * 8);  \
        }                                                                      \
        _Pragma("unroll")                                                      \
        for (int r = 0; r < 4; r++) {                                          \
            int idx = r * 256 + t;                                             \
            int row = idx >> 3;                                                \
            int kq = ((idx & 7) - (row >> 1)) & 7;                             \
            gl_lds16(Bb + (size_t)row * DIM + (koff) + kq * 8, lB + idx * 8);  \
        }                                                                      \
    }

#define GEMM_COMPUTE(lA, lB, acc)                                              \
    __builtin_amdgcn_s_setprio(1);                                             \
    _Pragma("unroll")                                                          \
    for (int h = 0; h < 2; h++) {                                              \
        const int swzh = (((h << 2) + quad + (l16 >> 1)) & 7) * 8;             \
        bf16x8 af[4], bfr[4];                                                  \
        _Pragma("unroll")                                                      \
        for (int mt = 0; mt < 4; mt++)                                         \
            af[mt] = *(const bf16x8*)((lA) + (wm * 64 + mt * 16 + l16) * 64 + swzh); \
        _Pragma("unroll")                                                      \
        for (int nt = 0; nt < 4; nt++)                                         \
            bfr[nt] = *(const bf16x8*)((lB) + (wn * 64 + nt * 16 + l16) * 64 + swzh); \
        _Pragma("unroll")                                                      \
        for (int mt = 0; mt < 4; mt++)                                         \
            _Pragma("unroll")                                                  \
            for (int nt = 0; nt < 4; nt++)                                     \
                acc[mt][nt] = __builtin_amdgcn_mfma_f32_16x16x32_bf16(         \
                    af[mt], bfr[nt], acc[mt][nt], 0, 0, 0);                    \
    }                                                                          \
    __builtin_amdgcn_s_setprio(0);

// one pipelined K-step: stage next tile, wait for current (8 newest stay in
// flight), barrier, compute current, fence ds_reads, barrier.
#define GEMM_KSTEP(cA, cB, sA, sB, koff)                                       \
    GEMM_STAGE(Ab, Bb, sA, sB, koff)                                           \
    asm volatile("s_waitcnt vmcnt(8)" ::: "memory");                           \
    __builtin_amdgcn_s_barrier();                                              \
    GEMM_COMPUTE(cA, cB, acc)                                                  \
    asm volatile("s_waitcnt lgkmcnt(0)" ::: "memory");                         \
    __builtin_amdgcn_s_barrier();

// 6 K-tiles (DIM=384, BK=64), fully unrolled.
#define GEMM_MAIN_LOOP_V6(Ab, Bb, acc)                                         \
    GEMM_STAGE(Ab, Bb, lA0, lB0, 0)                                            \
    GEMM_KSTEP(lA0, lB0, lA1, lB1, 64)                                         \
    GEMM_KSTEP(lA1, lB1, lA0, lB0, 128)                                        \
    GEMM_KSTEP(lA0, lB0, lA1, lB1, 192)                                        \
    GEMM_KSTEP(lA1, lB1, lA0, lB0, 256)                                        \
    GEMM_KSTEP(lA0, lB0, lA1, lB1, 320)                                        \
    asm volatile("s_waitcnt vmcnt(0)" ::: "memory");                           \
    __builtin_amdgcn_s_barrier();                                              \
    GEMM_COMPUTE(lA1, lB1, acc)

// ---------------------------------------------------------------------------
// Merged GEMM1+2, XCD-swizzled 1-D grid (2200 blocks).
// swz = (bid&7)*275 + bid>>3 ; m fastest (11 m-tiles of one xT panel run
// consecutively on one XCD), each XCD owns exactly batch b = bid&7.
// Per-XCD L2 set: 2.46 MB xT slice + 1.08 MB wcat < 4 MB.
// ---------------------------------------------------------------------------
__global__ __launch_bounds__(256) void gemm12_kernel(
        const bf16* __restrict__ A, const bf16* __restrict__ Bt,
        const float* __restrict__ bias, bf16* __restrict__ vP,
        bf16* __restrict__ lT) {
    __shared__ bf16 lds[32768];         // 2 x (lA 8192 | lB 8192) = 64 KB
    bf16* lA0 = lds;
    bf16* lB0 = lds + 8192;
    bf16* lA1 = lds + 16384;
    bf16* lB1 = lds + 24576;
    const int t = threadIdx.x;
    const int lane = t & 63, w = t >> 6;
    const int wm = w & 1, wn = w >> 1;
    const int quad = lane >> 4, l16 = lane & 15;

    const int bid = blockIdx.x;
    const int swz = (bid & 7) * 275 + (bid >> 3);
    const int mtile = swz % 11;          // fastest: panel reuse within XCD
    const int nb = swz / 11;             // [25b, 25b+25)
    const int ntile = nb % 25;
    const int b = nb / 25;               // == bid & 7
    const int n0 = ntile * 128;
    const int m0 = mtile * 128;

    const bf16* Ab = A + (size_t)m0 * DIM;
    const bf16* Bb = Bt + ((size_t)b * PP + n0) * DIM;

    f32x4 acc[4][4] = {};
    GEMM_MAIN_LOOP_V6(Ab, Bb, acc)

    const bool isv = (m0 < 384);
    const int ch0 = isv ? m0 : m0 - 384;

    // wbuf lives in buf0 (lA0); last buf0 readers (T4 compute) are fenced by
    // their own lgkmcnt(0)+barrier; T5 compute reads buf1 only -> disjoint.
    bf16* wbuf = lds + w * 1152;   // wave-private, row stride 72 bf16
    const int nr = lane >> 2;
    const int mc = (lane & 3) * 16;
#pragma unroll
    for (int nt = 0; nt < 4; nt++) {
#pragma unroll
        for (int mt = 0; mt < 4; mt++) {
            float4 bi = make_float4(0.f, 0.f, 0.f, 0.f);
            if (isv) bi = *(const float4*)(bias + ch0 + wm * 64 + mt * 16 + quad * 4);
            bf16x4v pk;
            pk[0] = f2bs(acc[mt][nt][0] + bi.x);
            pk[1] = f2bs(acc[mt][nt][1] + bi.y);
            pk[2] = f2bs(acc[mt][nt][2] + bi.z);
            pk[3] = f2bs(acc[mt][nt][3] + bi.w);
            *(bf16x4v*)(wbuf + l16 * 72 + mt * 16 + quad * 4) = pk;
        }
        bf16x8 v0 = *(const bf16x8*)(wbuf + nr * 72 + mc);
        bf16x8 v1 = *(const bf16x8*)(wbuf + nr * 72 + mc + 8);
        const int p = n0 + wn * 64 + nt * 16 + nr;
        const int cc = ch0 + wm * 64 + mc;          // channel base of this 16-chunk
        if (p < HWP && (isv || cc < AOP)) {
            bf16* dp;
            if (isv) {
                const int y = p / WW;          // padded canvas: (y+2)*60 + x+2
                dp = vP + ((size_t)b * PPAD + p + y * 4 + 122) * DIM + cc;
            } else {
                dp = lT + ((size_t)b * PP + p) * AOP + cc;
            }
            *(bf16x8*)dp = v0;
            *(bf16x8*)(dp + 8) = v1;
        }
    }
}

// ---------------------------------------------------------------------------
// GEMM4: planar fp32 out [b][384][3136]. XCD-swizzled 1-D grid (600 blocks):
// swz = (bid&7)*75 + bid>>3 ; m fastest, each XCD owns batch b = bid&7.
// ---------------------------------------------------------------------------
__global__ __launch_bounds__(256) void gemm_planar_kernel(
        const bf16* __restrict__ A, const bf16* __restrict__ Bt,
        float* __restrict__ out) {
    __shared__ bf16 lds[32768];
    bf16* lA0 = lds;
    bf16* lB0 = lds + 8192;
    bf16* lA1 = lds + 16384;
    bf16* lB1 = lds + 24576;
    const int t = threadIdx.x;
    const int lane = t & 63, w = t >> 6;
    const int wm = w & 1, wn = w >> 1;
    const int quad = lane >> 4, l16 = lane & 15;

    const int bid = blockIdx.x;
    const int swz = (bid & 7) * 75 + (bid >> 3);
    const int mtile = swz % 3;
    const int nb = swz / 3;
    const int ntile = nb % 25;
    const int b = nb / 25;
    const int n0 = ntile * 128;
    const int m0 = mtile * 128;

    const bf16* Ab = A + (size_t)m0 * DIM;
    const bf16* Bb = Bt + ((size_t)b * PP + n0) * DIM;

    f32x4 acc[4][4] = {};
    GEMM_MAIN_LOOP_V6(Ab, Bb, acc)

#pragma unroll
    for (int mt = 0; mt < 4; mt++) {
#pragma unroll
        for (int nt = 0; nt < 4; nt++) {
            int p = n0 + wn * 64 + nt * 16 + l16;
            if (p >= HWP) continue;
#pragma unroll
            for (int reg = 0; reg < 4; reg++) {
                int o = m0 + wm * 64 + mt * 16 + quad * 4 + reg;
                out[((size_t)b * DIM + o) * HWP + p] = acc[mt][nt][reg];
            }
        }
    }
}

// ---------------------------------------------------------------------------
// attn+fold: 8 pixels per block, 384 threads (round-5 structure restored).
// 1-D grid 3136 blocks: b = bid&7 (each XCD owns one batch).
// Stage A reads the PERMUTED lT layout: channel c' = n*81 + i*9 + d ->
// each thread's 9 logits are 18 contiguous bytes (1 line-miss + 8 L1 hits).
// ---------------------------------------------------------------------------
__global__ __launch_bounds__(384) void attn_fold_kernel(
        const bf16* __restrict__ lT, const bf16* __restrict__ vP,
        bf16* __restrict__ cT) {
    __shared__ bf16 P[8 * 9 * 12 * 9];     // [px][i][n][d]  19440 B
    __shared__ float Wf[8 * 25 * 12];      // [px][off][n]    9600 B
    const int t = threadIdx.x;
    const int b = blockIdx.x & 7;
    const int pix0 = (blockIdx.x >> 3) * 8;
    const int Y = pix0 / WW, X0 = pix0 % WW;

    // ---- stage A: softmaxes at window centers (contiguous 9-short reads)
    for (int r = t; r < 864; r += 384) {
        const int px = r / 108, rem = r % 108;
        const int i = rem / 12, n = rem % 12;
        const int ir = i / 3, ic = i % 3;
        const int yi = Y + 1 - ir, xi = X0 + px + 1 - ic;
        bf16* Pd = &P[r * 9];   // r*9 == ((px*9+i)*12+n)*9
        if (yi < 0 || yi >= HH || xi < 0 || xi >= WW) {
#pragma unroll
            for (int d = 0; d < K2; d++) *(short*)&Pd[d] = 0;
        } else {
            const bf16* base = lT + ((size_t)b * PP + yi * WW + xi) * AOP + n * 81 + i * 9;
            float lv[K2];
            float m = -1e30f;
#pragma unroll
            for (int d = 0; d < K2; d++) {
                lv[d] = b2f(base[d]);
                m = fmaxf(m, lv[d]);
            }
            float s = 0.f;
#pragma unroll
            for (int d = 0; d < K2; d++) { lv[d] = __expf(lv[d] - m); s += lv[d]; }
            const float inv = 1.f / s;
#pragma unroll
            for (int d = 0; d < K2; d++) *(short*)&Pd[d] = f2bs(lv[d] * inv);
        }
    }
    __syncthreads();

    // ---- stage B: effective 5x5 weights; thread owns (off,n), loops px
    if (t < 300) {
        const int off = t / 12, n = t % 12;
        const int dy = off / 5 - 2, dx = off % 5 - 2;
        const int ir_lo = max(0, -dy), ir_hi = min(2, 2 - dy);
        const int ic_lo = max(0, -dx), ic_hi = min(2, 2 - dx);
#pragma unroll
        for (int px = 0; px < 8; px++) {
            float wsum = 0.f;
            for (int ir = ir_lo; ir <= ir_hi; ir++)
                for (int ic = ic_lo; ic <= ic_hi; ic++) {
                    const int i = ir * 3 + ic;
                    const int d = (dy + ir) * 3 + (dx + ic);
                    wsum += b2f(P[((px * 9 + i) * 12 + n) * 9 + d]);
                }
            Wf[(px * 25 + off) * 12 + n] = wsum;
        }
    }
    __syncthreads();

    // ---- stage C: apply 5x5 gather on zero-padded canvas, packed fma
    const int px = t / 48, cg = t % 48;
    const int X = X0 + px;
    const int n = cg >> 2;
    const float* Wp = &Wf[px * 300 + n];
    const bf16* vbp = vP + ((size_t)b * PPAD + (size_t)(Y + 2) * W60 + (X + 2)) * DIM + cg * 8;
    f32x2 a2[4] = {};
#pragma unroll
    for (int dy = -2; dy <= 2; dy++) {
        const bf16* rowb = vbp + dy * (W60 * DIM);
        const float* wrow = Wp + (dy + 2) * 60;   // 5*12
#pragma unroll
        for (int dx = -2; dx <= 2; dx++) {
            const float w = wrow[(dx + 2) * 12];
            const uint4 d = *(const uint4*)(rowb + dx * DIM);
            f32x2 w2; w2[0] = w; w2[1] = w;
            a2[0] = __builtin_elementwise_fma(unpk(d.x), w2, a2[0]);
            a2[1] = __builtin_elementwise_fma(unpk(d.y), w2, a2[1]);
            a2[2] = __builtin_elementwise_fma(unpk(d.z), w2, a2[2]);
            a2[3] = __builtin_elementwise_fma(unpk(d.w), w2, a2[3]);
        }
    }
    bf16x8 po;
#pragma unroll
    for (int j = 0; j < 4; j++) {
        po[2 * j]     = f2bs(a2[j][0]);
        po[2 * j + 1] = f2bs(a2[j][1]);
    }
    *(bf16x8*)(cT + ((size_t)b * PP + pix0 + px) * DIM + cg * 8) = po;
}

// ---------------------------------------------------------------------------
extern "C" void kernel_launch(void* const* d_in, const int* in_sizes, int n_in,
                              void* d_out, int out_size, void* d_ws, size_t ws_size,
                              hipStream_t stream) {
    const float* x      = (const float*)d_in[0];
    const float* v_w    = (const float*)d_in[1];
    const float* v_b    = (const float*)d_in[2];
    const float* attn_w = (const float*)d_in[3];
    const float* proj_w = (const float*)d_in[4];
    float* out = (float*)d_out;

    bf16* xT    = (bf16*)d_ws;                        // [8][3200][384]
    bf16* vP    = xT + (size_t)BB * PP * DIM;         // [8][3600][384] padded canvas
    bf16* lT    = vP + (size_t)BB * PPAD * DIM;       // [8][3200][976]
    bf16* wcat  = lT + (size_t)BB * PP * AOP;         // [1408][384]
    bf16* wp    = wcat + (size_t)MCAT * DIM;          // [384][384]
    bf16* cT    = xT;   // canvasT aliases xT (xT dead after gemm12)

    const int nprep = 400 + WBLK + HALOBLK;
    prep_kernel<<<nprep, 256, 0, stream>>>(x, v_w, attn_w, proj_w, xT, wcat, wp, vP);

    // 1+2) value projection (-> padded canvas) + attention logits (merged)
    gemm12_kernel<<<2200, 256, 0, stream>>>(wcat, xT, v_b, vP, lT);
    // 3) fused softmax + weight-reduce + 5x5 gather -> cT
    attn_fold_kernel<<<3136, 384, 0, stream>>>(lT, vP, cT);
    // 4) output projection -> out (planar fp32)
    gemm_planar_kernel<<<600, 256, 0, stream>>>(wp, cT, out);
}